// Round 6
// baseline (499.880 us; speedup 1.0000x reference)
//
#include <hip/hip_runtime.h>
#include <hip/hip_bf16.h>

// Problem constants (match reference)
#define NN 100000
#define EE 1000000
#define FDIM 64
#define NREL 16
#define NBASE 8
#define HN (NN * FDIM)
#define H4 (HN / 4)
#define NB_SCAN ((NN + 255) / 256) // 391 scan blocks
#define TROWS 8                    // dst nodes per tile
#define TSTRIDE 580                // T row stride (floats): 16 rels * 36 + 4 pad
#define NBLK (NN / TROWS)          // 12500 tiles

typedef __attribute__((ext_vector_type(8))) short short8;
typedef __attribute__((ext_vector_type(4))) float f32x4;

static __device__ __forceinline__ ushort f2bf(float f) {
    __hip_bfloat16 b = __float2bfloat16(f);
    return *(ushort*)&b;
}
static __device__ __forceinline__ float bf2f(ushort u) {
    unsigned x = ((unsigned)u) << 16;
    float f;
    __builtin_memcpy(&f, &x, 4);
    return f;
}

// ---------------------------------------------------------------------------
// Algebra (harness-verified):
//   h2[n][o] = sum_k T[n][k] * weight_flat[k*64+o],  k = 32*rel + (q*8+b)
//   T[n][32*rel + j] += G[src][j];  G[s][q*8+b] = sum_m h[s][16q+m]*w_comp[m][b]
// G bf16 [N][32] (64-B rows). LDS T col for (rel,j) = rel*36+j.
// Tg (split path) holds T tiles as bf16 in MFMA-fragment order:
//   gi = (kk<<5)|(quad<<3)|row,  Tg[tile][gi][0..7] = T[row][kk*36+quad*8+e]
// ---------------------------------------------------------------------------

// prep2: zero cnt; bf16 weight transpose WbT[o][k=512]; G bf16 [N][32]; relu out.
__global__ __launch_bounds__(256) void prep2_kernel(
    const float4* __restrict__ h4, float4* __restrict__ out4,
    const float* __restrict__ h, const float* __restrict__ weight,
    const float* __restrict__ w_comp, ushort* __restrict__ G,
    ushort* __restrict__ WbTh, int* __restrict__ cnt) {
    __shared__ float wc[128];
    if (threadIdx.x < 128) wc[threadIdx.x] = w_comp[threadIdx.x];
    __syncthreads();
    int gid = blockIdx.x * 256 + threadIdx.x;
    if (gid < NN) cnt[gid] = 0;
    if (gid < 32768) {                       // WbT[o][k] = weight_flat[k*64+o]
        int o = gid >> 9, k = gid & 511;
        WbTh[gid] = f2bf(weight[k * 64 + o]);
    }
    if (gid < NN * 4) {                      // G[n][q*8+b] (bf16)
        int n = gid >> 2, q = gid & 3;
        const float4* hp = (const float4*)(h + (size_t)n * 64 + q * 16);
        float hv[16];
#pragma unroll
        for (int m4 = 0; m4 < 4; ++m4) {
            float4 v = hp[m4];
            hv[4 * m4 + 0] = v.x; hv[4 * m4 + 1] = v.y;
            hv[4 * m4 + 2] = v.z; hv[4 * m4 + 3] = v.w;
        }
        float accb[8];
#pragma unroll
        for (int b = 0; b < 8; ++b) accb[b] = 0.f;
#pragma unroll
        for (int m = 0; m < 16; ++m) {
            float hm = hv[m];
#pragma unroll
            for (int b = 0; b < 8; ++b)
                accb[b] = fmaf(hm, wc[m * 8 + b], accb[b]);
        }
        short8 gv;
#pragma unroll
        for (int b = 0; b < 8; ++b) gv[b] = (short)f2bf(accb[b]);
        ((short8*)G)[gid] = gv;
    }
    if (gid < H4) {                          // relu output
        float4 v = h4[gid];
        v.x = fmaxf(v.x, 0.f); v.y = fmaxf(v.y, 0.f);
        v.z = fmaxf(v.z, 0.f); v.w = fmaxf(v.w, 0.f);
        out4[gid] = v;
    }
}

// dst histogram (after cnt zeroed in prep2)
__global__ __launch_bounds__(256) void histn_kernel(const int* __restrict__ dst,
                                                    int* __restrict__ cnt) {
    int stride = gridDim.x * 256;
    for (int i = blockIdx.x * 256 + threadIdx.x; i < EE; i += stride)
        atomicAdd(&cnt[dst[i]], 1);
}

// ---- multi-block exclusive scan of the 100k dst-histogram (3 tiny stages) ----
__global__ __launch_bounds__(256) void scan_a_kernel(const int* __restrict__ cnt,
                                                     int* __restrict__ bsum) {
    int i = blockIdx.x * 256 + threadIdx.x;
    int v = (i < NN) ? cnt[i] : 0;
#pragma unroll
    for (int o = 32; o > 0; o >>= 1) v += __shfl_down(v, o, 64);
    __shared__ int ws4[4];
    if ((threadIdx.x & 63) == 0) ws4[threadIdx.x >> 6] = v;
    __syncthreads();
    if (threadIdx.x == 0) bsum[blockIdx.x] = ws4[0] + ws4[1] + ws4[2] + ws4[3];
}

__global__ __launch_bounds__(512) void scan_b_kernel(const int* __restrict__ bsum,
                                                     int* __restrict__ bbase,
                                                     int* __restrict__ off) {
    __shared__ int lds[512];
    int t = threadIdx.x;
    int v = (t < NB_SCAN) ? bsum[t] : 0;
    lds[t] = v;
    __syncthreads();
    for (int o = 1; o < 512; o <<= 1) {
        int u = (t >= o) ? lds[t - o] : 0;
        __syncthreads();
        lds[t] += u;
        __syncthreads();
    }
    if (t < NB_SCAN) bbase[t] = lds[t] - v;
    if (t == NB_SCAN - 1) off[NN] = lds[t];
}

__global__ __launch_bounds__(256) void scan_c_kernel(const int* __restrict__ cnt,
                                                     const int* __restrict__ bbase,
                                                     int* __restrict__ off,
                                                     int* __restrict__ cur) {
    __shared__ int lds[256];
    int i = blockIdx.x * 256 + threadIdx.x;
    int t = threadIdx.x;
    int v = (i < NN) ? cnt[i] : 0;
    lds[t] = v;
    __syncthreads();
    for (int o = 1; o < 256; o <<= 1) {
        int u = (t >= o) ? lds[t - o] : 0;
        __syncthreads();
        lds[t] += u;
        __syncthreads();
    }
    if (i < NN) {
        int excl = lds[t] - v + bbase[blockIdx.x];
        off[i] = excl;
        cur[i] = excl;
    }
}

// Bucket edges by dst; payload p = (src<<8) | ((dst&15)<<4) | rel.
__global__ void scatter_dst_kernel(const int* __restrict__ src, const int* __restrict__ dst,
                                   const int* __restrict__ rel, int* __restrict__ cur,
                                   int* __restrict__ pidx) {
    int i = blockIdx.x * blockDim.x + threadIdx.x;
    if (i < EE) {
        int d = dst[i];
        int pos = atomicAdd(&cur[d], 1);
        pidx[pos] = (src[i] << 8) | ((d & 15) << 4) | rel[i];
    }
}

// ============ SPLIT PATH: isolate the gather phase from the GEMM =============

// Edge gather + LDS-accumulate; dump T tiles as bf16 fragments to Tg.
// launch_bounds(256,4): VGPR<=128 so the unroll-4 gather keeps 16 edges in
// flight per wave (round 5's (256,8) forced VGPR=32 and serialized it).
__global__ __launch_bounds__(256, 4) void edge_accum_kernel(
    const int* __restrict__ off, const int* __restrict__ pidx,
    const ushort* __restrict__ G, ushort* __restrict__ Tg) {
    __shared__ __align__(16) float T[TROWS][TSTRIDE];
    int t = threadIdx.x;
    f32x4* Tz = (f32x4*)&T[0][0];
    for (int i = t; i < TROWS * TSTRIDE / 4; i += 256)
        Tz[i] = (f32x4){0.f, 0.f, 0.f, 0.f};
    __syncthreads();

    const int node0 = blockIdx.x * TROWS;
    const int wv = t >> 6;
    const int lane = t & 63;
    {
        const int eBeg = off[node0];
        const int eEnd = off[node0 + TROWS];
        const int cntE = eEnd - eBeg;
        const int q = (cntE + 3) >> 2;       // edges per wave
        int w0 = eBeg + wv * q;
        int w1 = w0 + q; if (w1 > eEnd) w1 = eEnd;
        const int esub = lane >> 4;          // 0..3 : edge within instr
        const int c = lane & 15;             // ushort2 index within 64-B G row
        const ushort2* G2 = (const ushort2*)G;
        int base = w0;
        for (; base + 16 <= w1; base += 16) {   // 16 edges in flight per wave
            int p0 = pidx[base + esub];
            int p1 = pidx[base + 4 + esub];
            int p2 = pidx[base + 8 + esub];
            int p3 = pidx[base + 12 + esub];
            ushort2 g0 = G2[(size_t)(p0 >> 8) * 16 + c];
            ushort2 g1 = G2[(size_t)(p1 >> 8) * 16 + c];
            ushort2 g2 = G2[(size_t)(p2 >> 8) * 16 + c];
            ushort2 g3 = G2[(size_t)(p3 >> 8) * 16 + c];
            float* r0 = &T[(p0 >> 4) & 7][(p0 & 15) * 36 + 2 * c];
            float* r1 = &T[(p1 >> 4) & 7][(p1 & 15) * 36 + 2 * c];
            float* r2 = &T[(p2 >> 4) & 7][(p2 & 15) * 36 + 2 * c];
            float* r3 = &T[(p3 >> 4) & 7][(p3 & 15) * 36 + 2 * c];
            atomicAdd(r0, bf2f(g0.x)); atomicAdd(r0 + 1, bf2f(g0.y));
            atomicAdd(r1, bf2f(g1.x)); atomicAdd(r1 + 1, bf2f(g1.y));
            atomicAdd(r2, bf2f(g2.x)); atomicAdd(r2 + 1, bf2f(g2.y));
            atomicAdd(r3, bf2f(g3.x)); atomicAdd(r3 + 1, bf2f(g3.y));
        }
        for (; base < w1; base += 4) {
            int el = base + esub;
            if (el < w1) {
                int p0 = pidx[el];
                ushort2 g0 = G2[(size_t)(p0 >> 8) * 16 + c];
                float* r0 = &T[(p0 >> 4) & 7][(p0 & 15) * 36 + 2 * c];
                atomicAdd(r0, bf2f(g0.x)); atomicAdd(r0 + 1, bf2f(g0.y));
            }
        }
    }
    __syncthreads();

    // Dump T -> Tg in MFMA fragment order (gi = kk<<5 | quad<<3 | row).
    short8* Tg8 = (short8*)Tg + (size_t)blockIdx.x * 512;
#pragma unroll
    for (int s = 0; s < 2; ++s) {
        int gi = t * 2 + s;
        int kk = gi >> 5, quad = (gi >> 3) & 3, row = gi & 7;
        const float* ap = &T[row][kk * 36 + quad * 8];
        f32x4 a0 = *(const f32x4*)ap;
        f32x4 a1 = *(const f32x4*)(ap + 4);
        short8 v;
#pragma unroll
        for (int i = 0; i < 4; ++i) {
            v[i] = (short)f2bf(a0[i]);
            v[4 + i] = (short)f2bf(a1[i]);
        }
        Tg8[gi] = v;
    }
}

// Streaming fragment-GEMM: [8x512] tile (bf16, fragment-ordered) @ [512x64].
// A reads are fully coalesced 512-B regions per kk; numerics identical to the
// fused version (T rounded to bf16 exactly once before MFMA).
__global__ __launch_bounds__(256, 4) void proj_kernel(
    const ushort* __restrict__ Tg, const ushort* __restrict__ WbTh,
    float* __restrict__ h2) {
    int t = threadIdx.x;
    const int wv = t >> 6, lane = t & 63;
    const int quad = lane >> 4, l15 = lane & 15;
    const short8* A8 = (const short8*)Tg + (size_t)blockIdx.x * 512;
    const short8* bh = (const short8*)(WbTh + (size_t)(wv * 16 + l15) * 512);
    f32x4 acc = (f32x4){0.f, 0.f, 0.f, 0.f};
#pragma unroll
    for (int kk = 0; kk < 16; ++kk) {
        short8 af = A8[(kk << 5) + (quad << 3) + (l15 & 7)];
        acc = __builtin_amdgcn_mfma_f32_16x16x32_bf16(af, bh[kk * 4 + quad], acc, 0, 0, 0);
    }
    // C/D: col = lane&15, row = quad*4 + reg; rows 0..7 valid (quad<2).
    if (quad < 2) {
        float* hp = h2 + (size_t)(blockIdx.x * TROWS + quad * 4) * 64 + wv * 16 + l15;
#pragma unroll
        for (int r = 0; r < 4; ++r)
            hp[(size_t)r * 64] = acc[r];
    }
}

// ============ FALLBACK: fused agg+proj (round-5, proven) =====================
__global__ __launch_bounds__(256, 8) void agg_proj_kernel(
    const int* __restrict__ off, const int* __restrict__ pidx,
    const ushort* __restrict__ G, const ushort* __restrict__ WbTh,
    float* __restrict__ h2) {
    __shared__ __align__(16) float T[TROWS][TSTRIDE];
    int t = threadIdx.x;
    f32x4* Tz = (f32x4*)&T[0][0];
    for (int i = t; i < TROWS * TSTRIDE / 4; i += 256)
        Tz[i] = (f32x4){0.f, 0.f, 0.f, 0.f};
    __syncthreads();
    const int node0 = blockIdx.x * TROWS;
    const int wv = t >> 6;
    const int lane = t & 63;
    {
        const int eBeg = off[node0];
        const int eEnd = off[node0 + TROWS];
        const int cntE = eEnd - eBeg;
        const int q = (cntE + 3) >> 2;
        int w0 = eBeg + wv * q;
        int w1 = w0 + q; if (w1 > eEnd) w1 = eEnd;
        const int esub = lane >> 4;
        const int c = lane & 15;
        const ushort2* G2 = (const ushort2*)G;
        for (int base = w0; base < w1; base += 4) {
            int el = base + esub;
            if (el < w1) {
                int p0 = pidx[el];
                ushort2 g0 = G2[(size_t)(p0 >> 8) * 16 + c];
                float* r0 = &T[(p0 >> 4) & 7][(p0 & 15) * 36 + 2 * c];
                atomicAdd(r0, bf2f(g0.x)); atomicAdd(r0 + 1, bf2f(g0.y));
            }
        }
    }
    __syncthreads();
    const int quad = lane >> 4, l15 = lane & 15;
    f32x4 acc = (f32x4){0.f, 0.f, 0.f, 0.f};
    const short8* bh = (const short8*)(WbTh + (size_t)(wv * 16 + l15) * 512);
#pragma unroll
    for (int kk = 0; kk < 16; ++kk) {
        const float* ap = &T[l15 & 7][kk * 36 + quad * 8];
        f32x4 a0 = *(const f32x4*)ap;
        f32x4 a1 = *(const f32x4*)(ap + 4);
        short8 ah;
#pragma unroll
        for (int i = 0; i < 4; ++i) {
            ah[i] = (short)f2bf(a0[i]);
            ah[4 + i] = (short)f2bf(a1[i]);
        }
        acc = __builtin_amdgcn_mfma_f32_16x16x32_bf16(ah, bh[kk * 4 + quad], acc, 0, 0, 0);
    }
    if (quad < 2) {
        float* hp = h2 + (size_t)(node0 + quad * 4) * 64 + wv * 16 + l15;
#pragma unroll
        for (int r = 0; r < 4; ++r)
            hp[(size_t)r * 64] = acc[r];
    }
}

extern "C" void kernel_launch(void* const* d_in, const int* in_sizes, int n_in,
                              void* d_out, int out_size, void* d_ws, size_t ws_size,
                              hipStream_t stream) {
    const float* h      = (const float*)d_in[0];
    const float* weight = (const float*)d_in[1];
    const float* w_comp = (const float*)d_in[2];
    const int*   src    = (const int*)d_in[3];
    const int*   dst    = (const int*)d_in[4];
    const int*   rel    = (const int*)d_in[5];

    float* out_hnew = (float*)d_out;
    float* out_h2   = out_hnew + HN;

    char* ws = (char*)d_ws;

    // Workspace layout (16B-aligned)
    ushort* WbTh  = (ushort*)ws;                    // 64 KB
    int*    cnt   = (int*)(ws + 131072);            // 100000 ints
    int*    off   = (int*)(ws + 531072);            // 100001 ints (+pad)
    int*    cur   = (int*)(ws + 931088);            // 100000 ints
    int*    pidx  = (int*)(ws + 1331088);           // 1M ints
    int*    bsum  = (int*)(ws + 5331088);           // 392 ints
    int*    bbase = (int*)(ws + 5332656);           // 392 ints
    ushort* G     = (ushort*)(ws + 5334224);        // N x 32 bf16 = 6.4 MB
    ushort* Tg    = (ushort*)(ws + 11734224);       // NBLK x 512 x 8 x 2B = 102.4 MB
    size_t need   = 11734224 + (size_t)NBLK * 8192; // ~114.1 MB

    hipLaunchKernelGGL(prep2_kernel, dim3(H4 / 256), dim3(256), 0, stream,
                       (const float4*)h, (float4*)out_hnew, h, weight, w_comp,
                       G, WbTh, cnt);
    hipLaunchKernelGGL(histn_kernel, dim3(1024), dim3(256), 0, stream, dst, cnt);
    hipLaunchKernelGGL(scan_a_kernel, dim3(NB_SCAN), dim3(256), 0, stream, cnt, bsum);
    hipLaunchKernelGGL(scan_b_kernel, dim3(1), dim3(512), 0, stream, bsum, bbase, off);
    hipLaunchKernelGGL(scan_c_kernel, dim3(NB_SCAN), dim3(256), 0, stream,
                       cnt, bbase, off, cur);
    hipLaunchKernelGGL(scatter_dst_kernel, dim3((EE + 255) / 256), dim3(256), 0, stream,
                       src, dst, rel, cur, pidx);
    if (ws_size >= need) {
        hipLaunchKernelGGL(edge_accum_kernel, dim3(NBLK), dim3(256), 0, stream,
                           off, pidx, G, Tg);
        hipLaunchKernelGGL(proj_kernel, dim3(NBLK), dim3(256), 0, stream,
                           Tg, WbTh, out_h2);
    } else {
        hipLaunchKernelGGL(agg_proj_kernel, dim3(NBLK), dim3(256), 0, stream,
                           off, pidx, G, WbTh, out_h2);
    }
}

// Round 7
// 352.612 us; speedup vs baseline: 1.4177x; 1.4177x over previous
//
#include <hip/hip_runtime.h>
#include <hip/hip_bf16.h>

// Problem constants (match reference)
#define NN 100000
#define EE 1000000
#define FDIM 64
#define NREL 16
#define NBASE 8
#define HN (NN * FDIM)
#define H4 (HN / 4)
#define NB_SCAN ((NN + 255) / 256) // 391 scan blocks
#define NBLK (NN / 8)              // 12500 blocks (8 nodes each)

typedef __attribute__((ext_vector_type(8))) short short8;
typedef __attribute__((ext_vector_type(4))) float f32x4;

static __device__ __forceinline__ ushort f2bf(float f) {
    __hip_bfloat16 b = __float2bfloat16(f);
    return *(ushort*)&b;
}
static __device__ __forceinline__ float bf2f(ushort u) {
    unsigned x = ((unsigned)u) << 16;
    float f;
    __builtin_memcpy(&f, &x, 4);
    return f;
}

// ---------------------------------------------------------------------------
// Algebra (harness-verified):
//   h2[n][o] = sum_k T[n][k] * weight_flat[k*64+o],  k = 32*rel + (q*8+b)
//   T[n][32*rel + j] += G[src][j];  G[s][q*8+b] = sum_m h[s][16q+m]*w_comp[m][b]
// Register mapping in the gather: lane L holds T[n][k] for k = L + 64*m
// (m = 0..7). An edge (src,r) contributes G[src][j] at k = 32r+j, i.e. to
// lanes with (L>>5) == (r&1) at reg m = r>>1, value column j = L&31.
// ---------------------------------------------------------------------------

// prep2: zero cnt; bf16 weight transpose WbT[o][k=512]; G bf16 [N][32]; relu out.
__global__ __launch_bounds__(256) void prep2_kernel(
    const float4* __restrict__ h4, float4* __restrict__ out4,
    const float* __restrict__ h, const float* __restrict__ weight,
    const float* __restrict__ w_comp, ushort* __restrict__ G,
    ushort* __restrict__ WbTh, int* __restrict__ cnt) {
    __shared__ float wc[128];
    if (threadIdx.x < 128) wc[threadIdx.x] = w_comp[threadIdx.x];
    __syncthreads();
    int gid = blockIdx.x * 256 + threadIdx.x;
    if (gid < NN) cnt[gid] = 0;
    if (gid < 32768) {                       // WbT[o][k] = weight_flat[k*64+o]
        int o = gid >> 9, k = gid & 511;
        WbTh[gid] = f2bf(weight[k * 64 + o]);
    }
    if (gid < NN * 4) {                      // G[n][q*8+b] (bf16)
        int n = gid >> 2, q = gid & 3;
        const float4* hp = (const float4*)(h + (size_t)n * 64 + q * 16);
        float hv[16];
#pragma unroll
        for (int m4 = 0; m4 < 4; ++m4) {
            float4 v = hp[m4];
            hv[4 * m4 + 0] = v.x; hv[4 * m4 + 1] = v.y;
            hv[4 * m4 + 2] = v.z; hv[4 * m4 + 3] = v.w;
        }
        float accb[8];
#pragma unroll
        for (int b = 0; b < 8; ++b) accb[b] = 0.f;
#pragma unroll
        for (int m = 0; m < 16; ++m) {
            float hm = hv[m];
#pragma unroll
            for (int b = 0; b < 8; ++b)
                accb[b] = fmaf(hm, wc[m * 8 + b], accb[b]);
        }
        short8 gv;
#pragma unroll
        for (int b = 0; b < 8; ++b) gv[b] = (short)f2bf(accb[b]);
        ((short8*)G)[gid] = gv;
    }
    if (gid < H4) {                          // relu output
        float4 v = h4[gid];
        v.x = fmaxf(v.x, 0.f); v.y = fmaxf(v.y, 0.f);
        v.z = fmaxf(v.z, 0.f); v.w = fmaxf(v.w, 0.f);
        out4[gid] = v;
    }
}

// dst histogram (after cnt zeroed in prep2)
__global__ __launch_bounds__(256) void histn_kernel(const int* __restrict__ dst,
                                                    int* __restrict__ cnt) {
    int stride = gridDim.x * 256;
    for (int i = blockIdx.x * 256 + threadIdx.x; i < EE; i += stride)
        atomicAdd(&cnt[dst[i]], 1);
}

// ---- multi-block exclusive scan of the 100k dst-histogram (3 tiny stages) ----
__global__ __launch_bounds__(256) void scan_a_kernel(const int* __restrict__ cnt,
                                                     int* __restrict__ bsum) {
    int i = blockIdx.x * 256 + threadIdx.x;
    int v = (i < NN) ? cnt[i] : 0;
#pragma unroll
    for (int o = 32; o > 0; o >>= 1) v += __shfl_down(v, o, 64);
    __shared__ int ws4[4];
    if ((threadIdx.x & 63) == 0) ws4[threadIdx.x >> 6] = v;
    __syncthreads();
    if (threadIdx.x == 0) bsum[blockIdx.x] = ws4[0] + ws4[1] + ws4[2] + ws4[3];
}

__global__ __launch_bounds__(512) void scan_b_kernel(const int* __restrict__ bsum,
                                                     int* __restrict__ bbase,
                                                     int* __restrict__ off) {
    __shared__ int lds[512];
    int t = threadIdx.x;
    int v = (t < NB_SCAN) ? bsum[t] : 0;
    lds[t] = v;
    __syncthreads();
    for (int o = 1; o < 512; o <<= 1) {
        int u = (t >= o) ? lds[t - o] : 0;
        __syncthreads();
        lds[t] += u;
        __syncthreads();
    }
    if (t < NB_SCAN) bbase[t] = lds[t] - v;
    if (t == NB_SCAN - 1) off[NN] = lds[t];
}

__global__ __launch_bounds__(256) void scan_c_kernel(const int* __restrict__ cnt,
                                                     const int* __restrict__ bbase,
                                                     int* __restrict__ off,
                                                     int* __restrict__ cur) {
    __shared__ int lds[256];
    int i = blockIdx.x * 256 + threadIdx.x;
    int t = threadIdx.x;
    int v = (i < NN) ? cnt[i] : 0;
    lds[t] = v;
    __syncthreads();
    for (int o = 1; o < 256; o <<= 1) {
        int u = (t >= o) ? lds[t - o] : 0;
        __syncthreads();
        lds[t] += u;
        __syncthreads();
    }
    if (i < NN) {
        int excl = lds[t] - v + bbase[blockIdx.x];
        off[i] = excl;
        cur[i] = excl;
    }
}

// Bucket edges by dst; payload p = src*16 + rel.
__global__ void scatter_dst_kernel(const int* __restrict__ src, const int* __restrict__ dst,
                                   const int* __restrict__ rel, int* __restrict__ cur,
                                   int* __restrict__ pidx) {
    int i = blockIdx.x * blockDim.x + threadIdx.x;
    if (i < EE) {
        int pos = atomicAdd(&cur[dst[i]], 1);
        pidx[pos] = (src[i] << 4) | rel[i];
    }
}

// Per-edge accumulate into lane registers (selected by r>>1 / half parity).
#define ACC8(p, gu)                                                          \
    {                                                                        \
        int r_ = (p) & 15;                                                   \
        float gv_ = ((r_ & 1) == half) ? bf2f(gu) : 0.f;                     \
        int m_ = r_ >> 1;                                                    \
        a0 += (m_ == 0) ? gv_ : 0.f;                                         \
        a1 += (m_ == 1) ? gv_ : 0.f;                                         \
        a2 += (m_ == 2) ? gv_ : 0.f;                                         \
        a3 += (m_ == 3) ? gv_ : 0.f;                                         \
        a4 += (m_ == 4) ? gv_ : 0.f;                                         \
        a5 += (m_ == 5) ? gv_ : 0.f;                                         \
        a6 += (m_ == 6) ? gv_ : 0.f;                                         \
        a7 += (m_ == 7) ? gv_ : 0.f;                                         \
    }

// Fused aggregate + projection, old-session gather micro-structure:
// 8 waves/block, ONE WAVE PER DST NODE, T accumulated in 8 registers/lane
// (no LDS, no atomics in the hot loop), 4-deep load batches. Then regs ->
// LDS T[8][516] (natural k layout), barrier, MFMA epilogue (waves 0-3).
__global__ __launch_bounds__(512, 8) void agg_proj_kernel(
    const int* __restrict__ off, const int* __restrict__ pidx,
    const ushort* __restrict__ G, const ushort* __restrict__ WbTh,
    float* __restrict__ h2) {
    __shared__ __align__(16) float T[8][516];
    const int t = threadIdx.x;
    const int wv = t >> 6;
    const int lane = t & 63;
    const int node0 = blockIdx.x * 8;

    {   // ---- gather: this wave owns node node0+wv ----
        const int node = node0 + wv;
        const int s = off[node], e = off[node + 1];
        const int col = lane & 31;           // j within the 32-value G row
        const int half = lane >> 5;          // parity selector
        float a0 = 0.f, a1 = 0.f, a2 = 0.f, a3 = 0.f;
        float a4 = 0.f, a5 = 0.f, a6 = 0.f, a7 = 0.f;
        int i = s;
        for (; i + 4 <= e; i += 4) {         // 4 independent row loads in flight
            int p0 = pidx[i], p1 = pidx[i + 1], p2 = pidx[i + 2], p3 = pidx[i + 3];
            ushort g0 = G[(size_t)(p0 >> 4) * 32 + col];
            ushort g1 = G[(size_t)(p1 >> 4) * 32 + col];
            ushort g2 = G[(size_t)(p2 >> 4) * 32 + col];
            ushort g3 = G[(size_t)(p3 >> 4) * 32 + col];
            ACC8(p0, g0); ACC8(p1, g1); ACC8(p2, g2); ACC8(p3, g3);
        }
        for (; i < e; ++i) {
            int p0 = pidx[i];
            ushort g0 = G[(size_t)(p0 >> 4) * 32 + col];
            ACC8(p0, g0);
        }
        // regs -> LDS row wv: lane L holds k = L + 64m (conflict-free stores)
        T[wv][lane +   0] = a0; T[wv][lane +  64] = a1;
        T[wv][lane + 128] = a2; T[wv][lane + 192] = a3;
        T[wv][lane + 256] = a4; T[wv][lane + 320] = a5;
        T[wv][lane + 384] = a6; T[wv][lane + 448] = a7;
    }
    __syncthreads();

    if (wv < 4) {   // ---- MFMA epilogue: [8x512] @ [512x64], proven layout ----
        const int quad = lane >> 4, l15 = lane & 15;
        f32x4 acc = (f32x4){0.f, 0.f, 0.f, 0.f};
        const short8* bh = (const short8*)(WbTh + (size_t)(wv * 16 + l15) * 512);
#pragma unroll
        for (int kk = 0; kk < 16; ++kk) {
            const float* ap = &T[l15 & 7][kk * 32 + quad * 8];
            f32x4 q0 = *(const f32x4*)ap;
            f32x4 q1 = *(const f32x4*)(ap + 4);
            short8 ah;
#pragma unroll
            for (int i = 0; i < 4; ++i) {
                ah[i] = (short)f2bf(q0[i]);
                ah[4 + i] = (short)f2bf(q1[i]);
            }
            acc = __builtin_amdgcn_mfma_f32_16x16x32_bf16(ah, bh[kk * 4 + quad], acc, 0, 0, 0);
        }
        // C/D: col = lane&15, row = quad*4 + reg; rows 0..7 valid (quad<2).
        if (quad < 2) {
            float* hp = h2 + (size_t)(node0 + quad * 4) * 64 + wv * 16 + l15;
#pragma unroll
            for (int r = 0; r < 4; ++r)
                hp[(size_t)r * 64] = acc[r];
        }
    }
}

extern "C" void kernel_launch(void* const* d_in, const int* in_sizes, int n_in,
                              void* d_out, int out_size, void* d_ws, size_t ws_size,
                              hipStream_t stream) {
    const float* h      = (const float*)d_in[0];
    const float* weight = (const float*)d_in[1];
    const float* w_comp = (const float*)d_in[2];
    const int*   src    = (const int*)d_in[3];
    const int*   dst    = (const int*)d_in[4];
    const int*   rel    = (const int*)d_in[5];

    float* out_hnew = (float*)d_out;
    float* out_h2   = out_hnew + HN;

    char* ws = (char*)d_ws;

    // Workspace layout (16B-aligned); total ~12 MB
    ushort* WbTh  = (ushort*)ws;                    // 64 KB
    int*    cnt   = (int*)(ws + 131072);            // 100000 ints
    int*    off   = (int*)(ws + 531072);            // 100001 ints (+pad)
    int*    cur   = (int*)(ws + 931088);            // 100000 ints
    int*    pidx  = (int*)(ws + 1331088);           // 1M ints
    int*    bsum  = (int*)(ws + 5331088);           // 392 ints
    int*    bbase = (int*)(ws + 5332656);           // 392 ints
    ushort* G     = (ushort*)(ws + 5334224);        // N x 32 bf16 = 6.4 MB

    hipLaunchKernelGGL(prep2_kernel, dim3(H4 / 256), dim3(256), 0, stream,
                       (const float4*)h, (float4*)out_hnew, h, weight, w_comp,
                       G, WbTh, cnt);
    hipLaunchKernelGGL(histn_kernel, dim3(1024), dim3(256), 0, stream, dst, cnt);
    hipLaunchKernelGGL(scan_a_kernel, dim3(NB_SCAN), dim3(256), 0, stream, cnt, bsum);
    hipLaunchKernelGGL(scan_b_kernel, dim3(1), dim3(512), 0, stream, bsum, bbase, off);
    hipLaunchKernelGGL(scan_c_kernel, dim3(NB_SCAN), dim3(256), 0, stream,
                       cnt, bbase, off, cur);
    hipLaunchKernelGGL(scatter_dst_kernel, dim3((EE + 255) / 256), dim3(256), 0, stream,
                       src, dst, rel, cur, pidx);
    hipLaunchKernelGGL(agg_proj_kernel, dim3(NBLK), dim3(512), 0, stream,
                       off, pidx, G, WbTh, out_h2);
}